// Round 12
// baseline (605.051 us; speedup 1.0000x reference)
//
#include <hip/hip_runtime.h>
#include <hip/hip_bf16.h>

#define N1 8192
#define N2 8192
#define CDIM 128
#define HC 60
#define WC 80
#define HIMG 480
#define WIMG 640
#define NPIX (HC * WC)
#define INV_DENOM (1.0f / (8192.0f * 256.0f))
#define PADK 136            // LDS row stride (128 + 8 ushort): keeps 16B align

using bf16x8 = __attribute__((ext_vector_type(8))) short;
using f32x4  = __attribute__((ext_vector_type(4))) float;

__device__ __forceinline__ ushort f2bf(float f) {
    union { float f; unsigned u; } x; x.f = f;
    unsigned u = x.u;
    unsigned r = (u + 0x7FFFu + ((u >> 16) & 1u)) >> 16;
    return (ushort)r;
}
__device__ __forceinline__ float bf2f(unsigned bits) {
    union { unsigned u; float f; } x; x.u = bits << 16; return x.f;
}
__device__ __forceinline__ unsigned key2bits(unsigned k) {
    return k ^ ((k & 0x8000u) ? 0x8000u : 0xFFFFu);
}
__device__ __forceinline__ unsigned pair2key(unsigned x) {   // fallback only
    return x ^ 0x80008000u ^ (((x >> 15) & 0x00010001u) * 0x7FFFu);
}

// ---------- fused prep + transpose (R12: one launch instead of two) ----------
// Blocks [0, 2048): cvt A,B to bf16 (R9 prep verbatim). Blocks [2048, 2648):
// LDS-tiled desc2 transpose (R9 tr verbatim, flat 256-thread indexing).
// Block 0 also zeroes the select-completion counter (stream-ordered before
// any select dispatch).
__global__ void prep_tr_kernel(const float* __restrict__ kp1d,
                               const float* __restrict__ kp2d,
                               const float* __restrict__ desc2,
                               ushort* __restrict__ Abf, ushort* __restrict__ Bbf,
                               float* __restrict__ d2T,
                               unsigned* __restrict__ ctr) {
    const int n4 = N1 * CDIM / 4;        // 262144
    const int t = threadIdx.x;
    const int b = blockIdx.x;
    if (b == 0 && t == 0) *ctr = 0u;

    if (b < 2048) {
        int i = b * 256 + t;
        if (i < n4) {
            float4 v = ((const float4*)kp1d)[i];
            ushort4 o;
            o.x = f2bf(v.x); o.y = f2bf(v.y); o.z = f2bf(v.z); o.w = f2bf(v.w);
            ((ushort4*)Abf)[i] = o;
        } else {
            int k = i - n4;
            float4 v = ((const float4*)kp2d)[k];
            ushort4 o;
            o.x = f2bf(v.x); o.y = f2bf(v.y); o.z = f2bf(v.z); o.w = f2bf(v.w);
            ((ushort4*)Bbf)[k] = o;
        }
    } else {
        __shared__ float tile[32][33];
        const int bb = b - 2048;                 // 0..599
        const int tx = t & 31, ty = t >> 5;      // 32 x 8
        const int p0 = (bb % 150) * 32;          // pixel tile
        const int c0 = (bb / 150) * 32;          // channel tile
        #pragma unroll
        for (int k = 0; k < 4; k++) {
            int c = c0 + ty + k * 8;
            tile[ty + k * 8][tx] = desc2[(size_t)c * NPIX + p0 + tx];
        }
        __syncthreads();
        #pragma unroll
        for (int k = 0; k < 4; k++) {
            int p = p0 + ty + k * 8;
            d2T[(size_t)p * CDIM + c0 + tx] = tile[tx][ty + k * 8];
        }
    }
}

// ---------- positive term (R9 verbatim) ----------
__global__ void pos_kernel(const float* __restrict__ wkp1,
                           const float* __restrict__ kp1d,
                           const float* __restrict__ desc2T,
                           float* __restrict__ ploss) {
    const int i = blockIdx.x;
    const int c = threadIdx.x;            // 128 threads = 2 waves
    float y = wkp1[2 * i], x = wkp1[2 * i + 1];
    float py = fminf(fmaxf(y / (float)(HIMG - 1) * (float)(HC - 1), 0.0f), (float)(HC - 1));
    float px = fminf(fmaxf(x / (float)(WIMG - 1) * (float)(WC - 1), 0.0f), (float)(WC - 1));
    int y0 = min(max((int)floorf(py), 0), HC - 2);
    int x0 = min(max((int)floorf(px), 0), WC - 2);
    float wy = py - (float)y0;
    float wx = px - (float)x0;
    const int p00 = y0 * WC + x0;
    float v00 = desc2T[(size_t)p00 * CDIM + c];
    float v01 = desc2T[(size_t)(p00 + 1) * CDIM + c];
    float v10 = desc2T[(size_t)(p00 + WC) * CDIM + c];
    float v11 = desc2T[(size_t)(p00 + WC + 1) * CDIM + c];
    float v = v00 * (1.0f - wy) * (1.0f - wx) + v01 * (1.0f - wy) * wx
            + v10 * wy * (1.0f - wx) + v11 * wy * wx;
    float a = kp1d[(size_t)i * CDIM + c];
    float s2 = v * v, sav = a * v;
    #pragma unroll
    for (int off = 32; off >= 1; off >>= 1) {
        s2  += __shfl_down(s2, off);
        sav += __shfl_down(sav, off);
    }
    __shared__ float p2[2], pav[2];
    int wave = threadIdx.x >> 6, lane = threadIdx.x & 63;
    if (lane == 0) { p2[wave] = s2; pav[wave] = sav; }
    __syncthreads();
    if (threadIdx.x == 0) {
        float nrm = sqrtf(p2[0] + p2[1]);
        float pd = (pav[0] + pav[1]) / fmaxf(nrm, 1e-12f);
        float l = fmaxf(1.0f - pd, 0.0f) * (256.0f / 3.0f);
        ploss[i] = l * INV_DENOM;
    }
}

// ---------- masked GEMM, LDS-staged, packed permuted stores (R9 verbatim) ----------
__global__ __launch_bounds__(256, 2)
void gemm_kernel(const ushort* __restrict__ A, const ushort* __restrict__ B,
                 const float* __restrict__ wkp1, const float* __restrict__ kp2,
                 ushort* __restrict__ dots, int m_off) {
    __shared__ ushort sA[128 * PADK];     // 34 KB
    __shared__ ushort sB[128 * PADK];     // 34 KB
    __shared__ float s_w[256], s_k[256];  // 2 KB coords

    const int t = threadIdx.x;
    const int n0 = blockIdx.x * 128;
    const int m0 = m_off + blockIdx.y * 128;

    s_w[t] = wkp1[2 * m0 + t];
    s_k[t] = kp2[2 * n0 + t];

    {
        const uint4* Ag = (const uint4*)(A + (size_t)m0 * CDIM);
        const uint4* Bg = (const uint4*)(B + (size_t)n0 * CDIM);
        #pragma unroll
        for (int r = 0; r < 8; r++) {
            int g = t + 256 * r;          // uint4 index 0..2047
            int row = g >> 4;
            int k8 = g & 15;
            uint4 va = Ag[g];
            uint4 vb = Bg[g];
            *(uint4*)(sA + row * PADK + k8 * 8) = va;
            *(uint4*)(sB + row * PADK + k8 * 8) = vb;
        }
    }
    __syncthreads();

    const int lane = t & 63;
    const int wave = t >> 6;
    const int wm = wave >> 1, wn = wave & 1;
    const int lrow = lane & 15, quad = lane >> 4;

    f32x4 acc[4][4];
    #pragma unroll
    for (int i = 0; i < 4; i++)
        #pragma unroll
        for (int j = 0; j < 4; j++) acc[i][j] = (f32x4){0.f, 0.f, 0.f, 0.f};

    #pragma unroll
    for (int kit = 0; kit < 4; kit++) {
        const int kk = kit * 32 + quad * 8;
        bf16x8 af[4], bfr[4];
        #pragma unroll
        for (int mt = 0; mt < 4; mt++)
            af[mt] = *(const bf16x8*)(sA + (wm * 64 + mt * 16 + lrow) * PADK + kk);
        #pragma unroll
        for (int nt = 0; nt < 4; nt++)
            bfr[nt] = *(const bf16x8*)(sB + (wn * 64 + nt * 16 + lrow) * PADK + kk);
        #pragma unroll
        for (int mt = 0; mt < 4; mt++)
            #pragma unroll
            for (int nt = 0; nt < 4; nt++)
                acc[mt][nt] = __builtin_amdgcn_mfma_f32_16x16x32_bf16(
                    af[mt], bfr[nt], acc[mt][nt], 0, 0, 0);
    }

    float ky[4], kx[4];
    #pragma unroll
    for (int nt = 0; nt < 4; nt++) {
        int jl = wn * 64 + nt * 16 + lrow;
        ky[nt] = s_k[2 * jl]; kx[nt] = s_k[2 * jl + 1];
    }
    const float thr = 2.0f * sqrtf(32.0f) + 0.1f;
    const float thr2 = thr * thr;
    const size_t colbase = (size_t)(n0 + wn * 64 + lrow * 4);
    #pragma unroll
    for (int mt = 0; mt < 4; mt++) {
        #pragma unroll
        for (int r = 0; r < 4; r++) {
            const int il = wm * 64 + mt * 16 + quad * 4 + r;      // local row
            const int i = m0 + il;
            const float wy = s_w[2 * il], wx = s_w[2 * il + 1];
            unsigned h[4];
            #pragma unroll
            for (int nt = 0; nt < 4; nt++) {
                float dy = wy - ky[nt], dx = wx - kx[nt];
                float v = acc[mt][nt][r];
                if (dy * dy + dx * dx <= thr2) v -= 5.0f;
                h[nt] = (unsigned)f2bf(v);
            }
            unsigned long long pk = (unsigned long long)(h[0] | (h[1] << 16))
                                  | ((unsigned long long)(h[2] | (h[3] << 16)) << 32);
            *(unsigned long long*)(dots + (size_t)(i - m_off) * N2 + colbase) = pk;
        }
    }
}

// ---------- per-row top-256 hinge histogram + last-block final reduce (R12) ----------
// Histogram/selection/fallback are R9 verbatim. New tail: lane0 fences +
// takes a ticket; the block drawing ticket N1-1 (all row losses + pos losses
// now visible: release-fence per block + stream order for pos) reproduces the
// old reduce_kernel's EXACT f32 summation order (4 per-lane partials emulate
// the 4 waves, same shfl tree, same 4-term final add) -> bit-identical out.
__global__ __launch_bounds__(256)
void select_kernel(const ushort* __restrict__ dots, float* __restrict__ loss,
                   unsigned* __restrict__ ctr, float* __restrict__ out,
                   int m_off) {
    const int g = m_off + blockIdx.x;            // global row
    const int t = threadIdx.x;
    const int lane = t & 63;

    __shared__ unsigned hist[193];
    __shared__ unsigned dmy[64];
    __shared__ unsigned hicnt;
    __shared__ ushort hlist[256];

    if (t < 193) hist[t] = 0u;
    if (t == 0) hicnt = 0u;
    __syncthreads();

    const uint4* rp4 = (const uint4*)(dots + (size_t)(g - m_off) * N2);  // 1024 uint4

    // ---- pass 1: histogram build (all 4 waves), 4 uint4 per thread
    #pragma unroll
    for (int j = 0; j < 4; j++) {
        uint4 w = rp4[t + 256 * j];
        unsigned xs[4] = {w.x, w.y, w.z, w.w};
        bool anyhi = false;
        #pragma unroll
        for (int q = 0; q < 4; q++) {
            unsigned lo = xs[q] & 0xFFFFu, hh = xs[q] >> 16;
            unsigned u0 = lo - 0x4141u, u1 = hh - 0x4141u;   // candidate iff < 0x3EBF
            unsigned b0 = min(u0, 192u), b1 = min(u1, 192u);
            unsigned* p0 = (u0 < 0x3EBFu) ? &hist[b0] : &dmy[lane];
            unsigned* p1 = (u1 < 0x3EBFu) ? &hist[b1] : &dmy[lane];
            atomicAdd(p0, 1u);
            atomicAdd(p1, 1u);
            anyhi |= ((u0 - 0xC0u) < 0x3DFFu) | ((u1 - 0xC0u) < 0x3DFFu);
        }
        if (__any(anyhi)) {                       // rare: values > 32.0
            #pragma unroll
            for (int q = 0; q < 4; q++) {
                unsigned lo = xs[q] & 0xFFFFu, hh = xs[q] >> 16;
                unsigned u0 = lo - 0x4141u, u1 = hh - 0x4141u;
                if ((u0 - 0xC0u) < 0x3DFFu) {
                    unsigned id = atomicAdd(&hicnt, 1u);
                    if (id < 255u) hlist[id] = (ushort)lo;
                }
                if ((u1 - 0xC0u) < 0x3DFFu) {
                    unsigned id = atomicAdd(&hicnt, 1u);
                    if (id < 255u) hlist[id] = (ushort)hh;
                }
            }
        }
    }
    __syncthreads();
    if (t >= 64) return;                          // wave0 continues; no barriers follow

    const int l = lane;
    unsigned c0 = hist[l], c1 = hist[64 + l], c2 = hist[128 + l];
    const unsigned nhi = hist[192];

    // inclusive suffix-scan across lanes for each 64-bin chunk
    unsigned s0i = c0, s1i = c1, s2i = c2;
    #pragma unroll
    for (int off = 1; off < 64; off <<= 1) {
        unsigned t0 = __shfl_down(s0i, off);
        unsigned t1 = __shfl_down(s1i, off);
        unsigned t2 = __shfl_down(s2i, off);
        if (l + off < 64) { s0i += t0; s1i += t1; s2i += t2; }
    }
    const unsigned T0 = __shfl(s0i, 0), T1 = __shfl(s1i, 0), T2 = __shfl(s2i, 0);
    const unsigned tot = nhi + T0 + T1 + T2;      // count of values > 12.0 (=totLow)

    // count of values STRICTLY greater than this lane's bin value
    const unsigned Ce0 = nhi + T1 + T2 + (s0i - c0);
    const unsigned Ce1 = nhi + T2 + (s1i - c1);
    const unsigned Ce2 = nhi + (s2i - c2);

    const bool ok = (tot >= 256u) && (nhi <= 255u);

    unsigned ktb;            // bf16 bits of 256th-largest (attained)
    double s = 0.0;
    int cgt = 0;

    if (ok) {
        unsigned long long m0 = __ballot(Ce0 < 256u);
        unsigned long long m1 = __ballot(Ce1 < 256u);
        unsigned long long m2 = __ballot(Ce2 < 256u);
        int bmin; unsigned cg;
        if (m0) { int fl = __ffsll((unsigned long long)m0) - 1; bmin = fl;       cg = __shfl(Ce0, fl); }
        else if (m1) { int fl = __ffsll((unsigned long long)m1) - 1; bmin = 64 + fl;  cg = __shfl(Ce1, fl); }
        else { int fl = __ffsll((unsigned long long)m2) - 1; bmin = 128 + fl; cg = __shfl(Ce2, fl); }
        ktb = 0x4141u + (unsigned)bmin;
        cgt = (int)cg;
        // per-bin hinge sums: cnt * (f32)(val - 0.2f), exact in f64
        if (l > bmin)       s += (double)c0 * (double)(bf2f(0x4141u + (unsigned)l) - 0.2f);
        if (64 + l > bmin)  s += (double)c1 * (double)(bf2f(0x4141u + 64u + (unsigned)l) - 0.2f);
        if (128 + l > bmin) s += (double)c2 * (double)(bf2f(0x4141u + 128u + (unsigned)l) - 0.2f);
        // values > 32.0 (all above threshold; counted inside Ce via nhi)
        for (unsigned p = (unsigned)l; p < nhi; p += 64u)
            s += (double)(bf2f(hlist[p]) - 0.2f);
        // fold per-lane f64 partials
        #pragma unroll
        for (int off = 32; off >= 1; off >>= 1) s += __shfl_down(s, off);
    } else {
        // ---- exact fallback: full-range key-domain bisect from global (full row)
        int lo = -1, hi = 65535;
        while (hi - lo > 1) {
            unsigned midu = (unsigned)((lo + hi) >> 1);
            unsigned midhi = (midu << 16) | 0xFFFFu;
            int c = 0;
            for (int j = 0; j < 16; j++) {
                uint4 w = rp4[l + 64 * j];
                unsigned xs[4] = {w.x, w.y, w.z, w.w};
                #pragma unroll
                for (int u = 0; u < 4; u++) {
                    unsigned kk = pair2key(xs[u]);
                    c += (int)((kk & 0xFFFFu) > midu) + (int)(kk > midhi);
                }
            }
            #pragma unroll
            for (int off = 32; off >= 1; off >>= 1) c += __shfl_down(c, off);
            c = __shfl(c, 0);
            if (c >= 256) lo = (int)midu; else hi = (int)midu;
        }
        unsigned kt = (unsigned)hi;
        const unsigned kthi = (kt << 16) | 0xFFFFu;
        for (int j = 0; j < 16; j++) {
            uint4 w = rp4[l + 64 * j];
            unsigned xs[4] = {w.x, w.y, w.z, w.w};
            #pragma unroll
            for (int u = 0; u < 4; u++) {
                unsigned kk = pair2key(xs[u]);
                unsigned lowk = kk & 0xFFFFu, highk = kk >> 16;
                if (lowk > kt) { s += (double)fmaxf(bf2f(key2bits(lowk))  - 0.2f, 0.f); cgt++; }
                if (kk > kthi) { s += (double)fmaxf(bf2f(key2bits(highk)) - 0.2f, 0.f); cgt++; }
            }
        }
        ktb = key2bits(kt);
        #pragma unroll
        for (int off = 32; off >= 1; off >>= 1) {
            s += __shfl_down(s, off);
            cgt += __shfl_down(cgt, off);
        }
    }

    if (l == 0) {
        float vt = bf2f(ktb);
        double S = s + (double)(256 - cgt) * (double)fmaxf(vt - 0.2f, 0.0f);
        loss[N1 + g] = (float)(S * (double)INV_DENOM);
    }

    // ---- last-block final reduce (replaces reduce_kernel launch)
    __threadfence();                              // release this block's loss write
    unsigned ticket = 0;
    if (l == 0) ticket = atomicAdd(ctr, 1u);
    ticket = __shfl(ticket, 0);
    if (ticket == (unsigned)(N1 - 1)) {
        __threadfence();                          // acquire all blocks' loss writes
        // reproduce old reduce_kernel f32 order exactly: emulate its 4 waves
        float sw[4] = {0.f, 0.f, 0.f, 0.f};
        #pragma unroll
        for (int k = 0; k < 4; k++)
            for (int i = k * 64 + l; i < 2 * N1; i += 256)
                sw[k] += loss[i];
        #pragma unroll
        for (int off = 32; off >= 1; off >>= 1) {
            sw[0] += __shfl_down(sw[0], off);
            sw[1] += __shfl_down(sw[1], off);
            sw[2] += __shfl_down(sw[2], off);
            sw[3] += __shfl_down(sw[3], off);
        }
        if (l == 0) out[0] = sw[0] + sw[1] + sw[2] + sw[3];
    }
}

extern "C" void kernel_launch(void* const* d_in, const int* in_sizes, int n_in,
                              void* d_out, int out_size, void* d_ws, size_t ws_size,
                              hipStream_t stream) {
    const float* wkp1  = (const float*)d_in[1];
    const float* kp2   = (const float*)d_in[2];
    const float* kp1d  = (const float*)d_in[3];
    const float* kp2d  = (const float*)d_in[4];
    const float* desc2 = (const float*)d_in[5];
    float* out = (float*)d_out;

    ushort*   Abf  = (ushort*)d_ws;                         // 2 MB
    ushort*   Bbf  = Abf + (size_t)N1 * CDIM;               // 2 MB
    float*    loss = (float*)(Bbf + (size_t)N2 * CDIM);     // 64 KB (pos | rows)
    float*    d2T  = loss + 2 * N1;                         // 2.4 MB
    unsigned* ctr  = (unsigned*)(d2T + (size_t)NPIX * CDIM);// 256 B (64 uints)
    ushort*   dots = (ushort*)(ctr + 64);                   // chunked dots

    size_t head_bytes = (size_t)(N1 + N2) * CDIM * sizeof(ushort)
                      + 2 * N1 * sizeof(float)
                      + (size_t)NPIX * CDIM * sizeof(float)
                      + 64 * sizeof(unsigned);
    size_t avail = (ws_size > head_bytes) ? (ws_size - head_bytes) : 0;
    long rows_chunk = (long)(avail / ((size_t)N2 * sizeof(ushort)));
    rows_chunk = (rows_chunk / 128) * 128;
    if (rows_chunk > N1) rows_chunk = N1;
    if (rows_chunk < 128) rows_chunk = 128;      // requires ws >= ~9 MB

    int n4 = N1 * CDIM / 4;
    int prep_blocks = (2 * n4) / 256 + (NPIX / 32) * (CDIM / 32);   // 2048 + 600
    prep_tr_kernel<<<prep_blocks, 256, 0, stream>>>(kp1d, kp2d, desc2,
                                                    Abf, Bbf, d2T, ctr);

    pos_kernel<<<N1, 128, 0, stream>>>(wkp1, kp1d, d2T, loss);

    for (int r0 = 0; r0 < N1; r0 += (int)rows_chunk) {
        int rows = (int)((N1 - r0 < rows_chunk) ? (N1 - r0) : rows_chunk);
        dim3 grid(N2 / 128, rows / 128);
        gemm_kernel<<<grid, 256, 0, stream>>>(Abf, Bbf, wkp1, kp2, dots, r0);
        select_kernel<<<rows, 256, 0, stream>>>(dots, loss, ctr, out, r0);
    }
}

// Round 13
// 162.196 us; speedup vs baseline: 3.7304x; 3.7304x over previous
//
#include <hip/hip_runtime.h>
#include <hip/hip_bf16.h>

#define N1 8192
#define N2 8192
#define CDIM 128
#define HC 60
#define WC 80
#define HIMG 480
#define WIMG 640
#define NPIX (HC * WC)
#define INV_DENOM (1.0f / (8192.0f * 256.0f))
#define PADK 136            // LDS row stride (128 + 8 ushort): keeps 16B align

using bf16x8 = __attribute__((ext_vector_type(8))) short;
using f32x4  = __attribute__((ext_vector_type(4))) float;

__device__ __forceinline__ ushort f2bf(float f) {
    union { float f; unsigned u; } x; x.f = f;
    unsigned u = x.u;
    unsigned r = (u + 0x7FFFu + ((u >> 16) & 1u)) >> 16;
    return (ushort)r;
}
__device__ __forceinline__ float bf2f(unsigned bits) {
    union { unsigned u; float f; } x; x.u = bits << 16; return x.f;
}
__device__ __forceinline__ unsigned key2bits(unsigned k) {
    return k ^ ((k & 0x8000u) ? 0x8000u : 0xFFFFu);
}
__device__ __forceinline__ unsigned pair2key(unsigned x) {   // fallback only
    return x ^ 0x80008000u ^ (((x >> 15) & 0x00010001u) * 0x7FFFu);
}

// ---------- fused prep + transpose (one launch; R12-verified structure,
// ticket counter removed) ----------
// Blocks [0, 2048): cvt A,B to bf16 (R9 prep verbatim). Blocks [2048, 2648):
// LDS-tiled desc2 transpose (R9 tr verbatim, flat 256-thread indexing).
__global__ void prep_tr_kernel(const float* __restrict__ kp1d,
                               const float* __restrict__ kp2d,
                               const float* __restrict__ desc2,
                               ushort* __restrict__ Abf, ushort* __restrict__ Bbf,
                               float* __restrict__ d2T) {
    const int n4 = N1 * CDIM / 4;        // 262144
    const int t = threadIdx.x;
    const int b = blockIdx.x;

    if (b < 2048) {
        int i = b * 256 + t;
        if (i < n4) {
            float4 v = ((const float4*)kp1d)[i];
            ushort4 o;
            o.x = f2bf(v.x); o.y = f2bf(v.y); o.z = f2bf(v.z); o.w = f2bf(v.w);
            ((ushort4*)Abf)[i] = o;
        } else {
            int k = i - n4;
            float4 v = ((const float4*)kp2d)[k];
            ushort4 o;
            o.x = f2bf(v.x); o.y = f2bf(v.y); o.z = f2bf(v.z); o.w = f2bf(v.w);
            ((ushort4*)Bbf)[k] = o;
        }
    } else {
        __shared__ float tile[32][33];
        const int bb = b - 2048;                 // 0..599
        const int tx = t & 31, ty = t >> 5;      // 32 x 8
        const int p0 = (bb % 150) * 32;          // pixel tile
        const int c0 = (bb / 150) * 32;          // channel tile
        #pragma unroll
        for (int k = 0; k < 4; k++) {
            int c = c0 + ty + k * 8;
            tile[ty + k * 8][tx] = desc2[(size_t)c * NPIX + p0 + tx];
        }
        __syncthreads();
        #pragma unroll
        for (int k = 0; k < 4; k++) {
            int p = p0 + ty + k * 8;
            d2T[(size_t)p * CDIM + c0 + tx] = tile[tx][ty + k * 8];
        }
    }
}

// ---------- positive term (R9 verbatim) ----------
__global__ void pos_kernel(const float* __restrict__ wkp1,
                           const float* __restrict__ kp1d,
                           const float* __restrict__ desc2T,
                           float* __restrict__ ploss) {
    const int i = blockIdx.x;
    const int c = threadIdx.x;            // 128 threads = 2 waves
    float y = wkp1[2 * i], x = wkp1[2 * i + 1];
    float py = fminf(fmaxf(y / (float)(HIMG - 1) * (float)(HC - 1), 0.0f), (float)(HC - 1));
    float px = fminf(fmaxf(x / (float)(WIMG - 1) * (float)(WC - 1), 0.0f), (float)(WC - 1));
    int y0 = min(max((int)floorf(py), 0), HC - 2);
    int x0 = min(max((int)floorf(px), 0), WC - 2);
    float wy = py - (float)y0;
    float wx = px - (float)x0;
    const int p00 = y0 * WC + x0;
    float v00 = desc2T[(size_t)p00 * CDIM + c];
    float v01 = desc2T[(size_t)(p00 + 1) * CDIM + c];
    float v10 = desc2T[(size_t)(p00 + WC) * CDIM + c];
    float v11 = desc2T[(size_t)(p00 + WC + 1) * CDIM + c];
    float v = v00 * (1.0f - wy) * (1.0f - wx) + v01 * (1.0f - wy) * wx
            + v10 * wy * (1.0f - wx) + v11 * wy * wx;
    float a = kp1d[(size_t)i * CDIM + c];
    float s2 = v * v, sav = a * v;
    #pragma unroll
    for (int off = 32; off >= 1; off >>= 1) {
        s2  += __shfl_down(s2, off);
        sav += __shfl_down(sav, off);
    }
    __shared__ float p2[2], pav[2];
    int wave = threadIdx.x >> 6, lane = threadIdx.x & 63;
    if (lane == 0) { p2[wave] = s2; pav[wave] = sav; }
    __syncthreads();
    if (threadIdx.x == 0) {
        float nrm = sqrtf(p2[0] + p2[1]);
        float pd = (pav[0] + pav[1]) / fmaxf(nrm, 1e-12f);
        float l = fmaxf(1.0f - pd, 0.0f) * (256.0f / 3.0f);
        ploss[i] = l * INV_DENOM;
    }
}

// ---------- masked GEMM, LDS-staged, packed permuted stores (R9 verbatim) ----------
__global__ __launch_bounds__(256, 2)
void gemm_kernel(const ushort* __restrict__ A, const ushort* __restrict__ B,
                 const float* __restrict__ wkp1, const float* __restrict__ kp2,
                 ushort* __restrict__ dots, int m_off) {
    __shared__ ushort sA[128 * PADK];     // 34 KB
    __shared__ ushort sB[128 * PADK];     // 34 KB
    __shared__ float s_w[256], s_k[256];  // 2 KB coords

    const int t = threadIdx.x;
    const int n0 = blockIdx.x * 128;
    const int m0 = m_off + blockIdx.y * 128;

    s_w[t] = wkp1[2 * m0 + t];
    s_k[t] = kp2[2 * n0 + t];

    {
        const uint4* Ag = (const uint4*)(A + (size_t)m0 * CDIM);
        const uint4* Bg = (const uint4*)(B + (size_t)n0 * CDIM);
        #pragma unroll
        for (int r = 0; r < 8; r++) {
            int g = t + 256 * r;          // uint4 index 0..2047
            int row = g >> 4;
            int k8 = g & 15;
            uint4 va = Ag[g];
            uint4 vb = Bg[g];
            *(uint4*)(sA + row * PADK + k8 * 8) = va;
            *(uint4*)(sB + row * PADK + k8 * 8) = vb;
        }
    }
    __syncthreads();

    const int lane = t & 63;
    const int wave = t >> 6;
    const int wm = wave >> 1, wn = wave & 1;
    const int lrow = lane & 15, quad = lane >> 4;

    f32x4 acc[4][4];
    #pragma unroll
    for (int i = 0; i < 4; i++)
        #pragma unroll
        for (int j = 0; j < 4; j++) acc[i][j] = (f32x4){0.f, 0.f, 0.f, 0.f};

    #pragma unroll
    for (int kit = 0; kit < 4; kit++) {
        const int kk = kit * 32 + quad * 8;
        bf16x8 af[4], bfr[4];
        #pragma unroll
        for (int mt = 0; mt < 4; mt++)
            af[mt] = *(const bf16x8*)(sA + (wm * 64 + mt * 16 + lrow) * PADK + kk);
        #pragma unroll
        for (int nt = 0; nt < 4; nt++)
            bfr[nt] = *(const bf16x8*)(sB + (wn * 64 + nt * 16 + lrow) * PADK + kk);
        #pragma unroll
        for (int mt = 0; mt < 4; mt++)
            #pragma unroll
            for (int nt = 0; nt < 4; nt++)
                acc[mt][nt] = __builtin_amdgcn_mfma_f32_16x16x32_bf16(
                    af[mt], bfr[nt], acc[mt][nt], 0, 0, 0);
    }

    float ky[4], kx[4];
    #pragma unroll
    for (int nt = 0; nt < 4; nt++) {
        int jl = wn * 64 + nt * 16 + lrow;
        ky[nt] = s_k[2 * jl]; kx[nt] = s_k[2 * jl + 1];
    }
    const float thr = 2.0f * sqrtf(32.0f) + 0.1f;
    const float thr2 = thr * thr;
    const size_t colbase = (size_t)(n0 + wn * 64 + lrow * 4);
    #pragma unroll
    for (int mt = 0; mt < 4; mt++) {
        #pragma unroll
        for (int r = 0; r < 4; r++) {
            const int il = wm * 64 + mt * 16 + quad * 4 + r;      // local row
            const int i = m0 + il;
            const float wy = s_w[2 * il], wx = s_w[2 * il + 1];
            unsigned h[4];
            #pragma unroll
            for (int nt = 0; nt < 4; nt++) {
                float dy = wy - ky[nt], dx = wx - kx[nt];
                float v = acc[mt][nt][r];
                if (dy * dy + dx * dx <= thr2) v -= 5.0f;
                h[nt] = (unsigned)f2bf(v);
            }
            unsigned long long pk = (unsigned long long)(h[0] | (h[1] << 16))
                                  | ((unsigned long long)(h[2] | (h[3] << 16)) << 32);
            *(unsigned long long*)(dots + (size_t)(i - m_off) * N2 + colbase) = pk;
        }
    }
}

// ---------- per-row top-256 hinge via REPLICATED 193-bin histogram (R13) ----------
// R9 select did one LDS atomicAdd per value into a single histogram; within a
// wave64 ds_add, lanes hitting the SAME bin serialize (same-address RMW), and
// the candidate distribution peaks sharply just above 12.0. R13: 8 sub-wave
// histogram copies hist[8][193] indexed by lane>>3 (stride 193 => copy k of
// bin b lands on bank (b+k)&31: 8 distinct banks, no new conflicts).
// Same-address collisions now only possible within 8-lane groups. The merge
// sums the 8 integer counts per bin before the scan -- counts bitwise equal
// to R9's, so threshold/sums/hlist/fallback are unchanged.
__global__ __launch_bounds__(256)
void select_kernel(const ushort* __restrict__ dots, float* __restrict__ rloss,
                   int m_off) {
    const int g = m_off + blockIdx.x;            // global row
    const int t = threadIdx.x;
    const int lane = t & 63;

    __shared__ unsigned hist[8][193];            // 6.0 KB, 8 sub-wave copies
    __shared__ unsigned dmy[64];
    __shared__ unsigned hicnt;
    __shared__ ushort hlist[256];

    unsigned* h1 = &hist[0][0];
    for (int i = t; i < 8 * 193; i += 256) h1[i] = 0u;
    if (t == 0) hicnt = 0u;
    __syncthreads();

    unsigned* myh = &hist[lane >> 3][0];
    const uint4* rp4 = (const uint4*)(dots + (size_t)(g - m_off) * N2);  // 1024 uint4

    // ---- pass 1: histogram build (all 4 waves), 4 uint4 per thread
    #pragma unroll
    for (int j = 0; j < 4; j++) {
        uint4 w = rp4[t + 256 * j];
        unsigned xs[4] = {w.x, w.y, w.z, w.w};
        bool anyhi = false;
        #pragma unroll
        for (int q = 0; q < 4; q++) {
            unsigned lo = xs[q] & 0xFFFFu, hh = xs[q] >> 16;
            unsigned u0 = lo - 0x4141u, u1 = hh - 0x4141u;   // candidate iff < 0x3EBF
            unsigned b0 = min(u0, 192u), b1 = min(u1, 192u);
            unsigned* p0 = (u0 < 0x3EBFu) ? &myh[b0] : &dmy[lane];
            unsigned* p1 = (u1 < 0x3EBFu) ? &myh[b1] : &dmy[lane];
            atomicAdd(p0, 1u);
            atomicAdd(p1, 1u);
            anyhi |= ((u0 - 0xC0u) < 0x3DFFu) | ((u1 - 0xC0u) < 0x3DFFu);
        }
        if (__any(anyhi)) {                       // rare: values > 32.0
            #pragma unroll
            for (int q = 0; q < 4; q++) {
                unsigned lo = xs[q] & 0xFFFFu, hh = xs[q] >> 16;
                unsigned u0 = lo - 0x4141u, u1 = hh - 0x4141u;
                if ((u0 - 0xC0u) < 0x3DFFu) {
                    unsigned id = atomicAdd(&hicnt, 1u);
                    if (id < 255u) hlist[id] = (ushort)lo;
                }
                if ((u1 - 0xC0u) < 0x3DFFu) {
                    unsigned id = atomicAdd(&hicnt, 1u);
                    if (id < 255u) hlist[id] = (ushort)hh;
                }
            }
        }
    }
    __syncthreads();
    if (t >= 64) return;                          // wave0 selects; no barriers follow

    const int l = lane;
    // merge the 8 copies: counts bitwise identical to R9's single histogram
    unsigned c0 = 0, c1 = 0, c2 = 0, nhi = 0;
    #pragma unroll
    for (int k = 0; k < 8; k++) {
        c0  += hist[k][l];
        c1  += hist[k][64 + l];
        c2  += hist[k][128 + l];
        nhi += hist[k][192];
    }

    // inclusive suffix-scan across lanes for each 64-bin chunk
    unsigned s0i = c0, s1i = c1, s2i = c2;
    #pragma unroll
    for (int off = 1; off < 64; off <<= 1) {
        unsigned t0 = __shfl_down(s0i, off);
        unsigned t1 = __shfl_down(s1i, off);
        unsigned t2 = __shfl_down(s2i, off);
        if (l + off < 64) { s0i += t0; s1i += t1; s2i += t2; }
    }
    const unsigned T0 = __shfl(s0i, 0), T1 = __shfl(s1i, 0), T2 = __shfl(s2i, 0);
    const unsigned tot = nhi + T0 + T1 + T2;      // count of values > 12.0 (=totLow)

    // count of values STRICTLY greater than this lane's bin value
    const unsigned Ce0 = nhi + T1 + T2 + (s0i - c0);
    const unsigned Ce1 = nhi + T2 + (s1i - c1);
    const unsigned Ce2 = nhi + (s2i - c2);

    const bool ok = (tot >= 256u) && (nhi <= 255u);

    unsigned ktb;            // bf16 bits of 256th-largest (attained)
    double s = 0.0;
    int cgt = 0;

    if (ok) {
        unsigned long long m0 = __ballot(Ce0 < 256u);
        unsigned long long m1 = __ballot(Ce1 < 256u);
        unsigned long long m2 = __ballot(Ce2 < 256u);
        int bmin; unsigned cg;
        if (m0) { int fl = __ffsll((unsigned long long)m0) - 1; bmin = fl;       cg = __shfl(Ce0, fl); }
        else if (m1) { int fl = __ffsll((unsigned long long)m1) - 1; bmin = 64 + fl;  cg = __shfl(Ce1, fl); }
        else { int fl = __ffsll((unsigned long long)m2) - 1; bmin = 128 + fl; cg = __shfl(Ce2, fl); }
        ktb = 0x4141u + (unsigned)bmin;
        cgt = (int)cg;
        // per-bin hinge sums: cnt * (f32)(val - 0.2f), exact in f64
        if (l > bmin)       s += (double)c0 * (double)(bf2f(0x4141u + (unsigned)l) - 0.2f);
        if (64 + l > bmin)  s += (double)c1 * (double)(bf2f(0x4141u + 64u + (unsigned)l) - 0.2f);
        if (128 + l > bmin) s += (double)c2 * (double)(bf2f(0x4141u + 128u + (unsigned)l) - 0.2f);
        // values > 32.0 (all above threshold; counted inside Ce via nhi)
        for (unsigned p = (unsigned)l; p < nhi; p += 64u)
            s += (double)(bf2f(hlist[p]) - 0.2f);
        // fold per-lane f64 partials
        #pragma unroll
        for (int off = 32; off >= 1; off >>= 1) s += __shfl_down(s, off);
    } else {
        // ---- exact fallback: full-range key-domain bisect from global (full row)
        int lo = -1, hi = 65535;
        while (hi - lo > 1) {
            unsigned midu = (unsigned)((lo + hi) >> 1);
            unsigned midhi = (midu << 16) | 0xFFFFu;
            int c = 0;
            for (int j = 0; j < 16; j++) {
                uint4 w = rp4[l + 64 * j];
                unsigned xs[4] = {w.x, w.y, w.z, w.w};
                #pragma unroll
                for (int u = 0; u < 4; u++) {
                    unsigned kk = pair2key(xs[u]);
                    c += (int)((kk & 0xFFFFu) > midu) + (int)(kk > midhi);
                }
            }
            #pragma unroll
            for (int off = 32; off >= 1; off >>= 1) c += __shfl_down(c, off);
            c = __shfl(c, 0);
            if (c >= 256) lo = (int)midu; else hi = (int)midu;
        }
        unsigned kt = (unsigned)hi;
        const unsigned kthi = (kt << 16) | 0xFFFFu;
        for (int j = 0; j < 16; j++) {
            uint4 w = rp4[l + 64 * j];
            unsigned xs[4] = {w.x, w.y, w.z, w.w};
            #pragma unroll
            for (int u = 0; u < 4; u++) {
                unsigned kk = pair2key(xs[u]);
                unsigned lowk = kk & 0xFFFFu, highk = kk >> 16;
                if (lowk > kt) { s += (double)fmaxf(bf2f(key2bits(lowk))  - 0.2f, 0.f); cgt++; }
                if (kk > kthi) { s += (double)fmaxf(bf2f(key2bits(highk)) - 0.2f, 0.f); cgt++; }
            }
        }
        ktb = key2bits(kt);
        #pragma unroll
        for (int off = 32; off >= 1; off >>= 1) {
            s += __shfl_down(s, off);
            cgt += __shfl_down(cgt, off);
        }
    }

    if (l == 0) {
        float vt = bf2f(ktb);
        double S = s + (double)(256 - cgt) * (double)fmaxf(vt - 0.2f, 0.0f);
        rloss[g] = (float)(S * (double)INV_DENOM);
    }
}

// ---------- final reduce: sum 2*N1 floats -> out[0] (R9 verbatim) ----------
__global__ void reduce_kernel(const float* __restrict__ a, float* __restrict__ out) {
    const int t = threadIdx.x;
    float s = 0.f;
    for (int i = t; i < 2 * N1; i += 256) s += a[i];
    #pragma unroll
    for (int off = 32; off >= 1; off >>= 1) s += __shfl_down(s, off);
    __shared__ float ws[4];
    int wave = t >> 6, lane = t & 63;
    if (lane == 0) ws[wave] = s;
    __syncthreads();
    if (t == 0) out[0] = ws[0] + ws[1] + ws[2] + ws[3];
}

extern "C" void kernel_launch(void* const* d_in, const int* in_sizes, int n_in,
                              void* d_out, int out_size, void* d_ws, size_t ws_size,
                              hipStream_t stream) {
    const float* wkp1  = (const float*)d_in[1];
    const float* kp2   = (const float*)d_in[2];
    const float* kp1d  = (const float*)d_in[3];
    const float* kp2d  = (const float*)d_in[4];
    const float* desc2 = (const float*)d_in[5];
    float* out = (float*)d_out;

    ushort* Abf   = (ushort*)d_ws;                         // 2 MB
    ushort* Bbf   = Abf + (size_t)N1 * CDIM;               // 2 MB
    float*  loss  = (float*)(Bbf + (size_t)N2 * CDIM);     // 64 KB (pos | rows)
    float*  d2T   = loss + 2 * N1;                         // 2.4 MB
    ushort* dots  = (ushort*)(d2T + (size_t)NPIX * CDIM);  // chunked dots

    size_t head_bytes = (size_t)(N1 + N2) * CDIM * sizeof(ushort)
                      + 2 * N1 * sizeof(float)
                      + (size_t)NPIX * CDIM * sizeof(float);
    size_t avail = (ws_size > head_bytes) ? (ws_size - head_bytes) : 0;
    long rows_chunk = (long)(avail / ((size_t)N2 * sizeof(ushort)));
    rows_chunk = (rows_chunk / 128) * 128;
    if (rows_chunk > N1) rows_chunk = N1;
    if (rows_chunk < 128) rows_chunk = 128;      // requires ws >= ~9 MB

    int n4 = N1 * CDIM / 4;
    int prep_blocks = (2 * n4) / 256 + (NPIX / 32) * (CDIM / 32);   // 2048 + 600
    prep_tr_kernel<<<prep_blocks, 256, 0, stream>>>(kp1d, kp2d, desc2,
                                                    Abf, Bbf, d2T);

    pos_kernel<<<N1, 128, 0, stream>>>(wkp1, kp1d, d2T, loss);

    for (int r0 = 0; r0 < N1; r0 += (int)rows_chunk) {
        int rows = (int)((N1 - r0 < rows_chunk) ? (N1 - r0) : rows_chunk);
        dim3 grid(N2 / 128, rows / 128);
        gemm_kernel<<<grid, 256, 0, stream>>>(Abf, Bbf, wkp1, kp2, dots, r0);
        select_kernel<<<rows, 256, 0, stream>>>(dots, loss + N1, r0);
    }

    reduce_kernel<<<1, 256, 0, stream>>>(loss, out);
}